// Round 13
// baseline (69.585 us; speedup 1.0000x reference)
//
#include <hip/hip_runtime.h>

#define NB 256
#define NS 2048
#define NP 64
#define ND 80
#define STILE 128
#define NTILE 16            // NS/STILE
#define NTHREADS 1024
#define LOG2E 1.4426950408889634f
#define BUFU 12672          // u16 per enc buffer
#define BUFBY 25344         // bytes per enc buffer

typedef __attribute__((ext_vector_type(4))) float f32x4;
typedef __attribute__((ext_vector_type(2))) __fp16 fp16x2;
typedef __attribute__((ext_vector_type(8))) _Float16 f16x8;
typedef __attribute__((ext_vector_type(4))) unsigned short u16x4;
typedef unsigned short u16;

// ---------------- LDS layout (bytes) ----------------
// buf[2] u16[8][6][264] @ 0      (50688)  f16 enc, 16x16 [s][d] row-major regions;
//        region(q,n) = (q*6+n)*264 u16; q = s>>4; n=5 = K-pad (zeroed once).
// mbias f32[2048]       @ 50688  (8192)   0.0 / -3e38 per s
// mst f32[8][64] @ 58880 (2048) ; lst f32[8][64] @ 60928 (2048) ; modep @ 62976
// prologue overlay: W f32[80][84]@0 ; dec f32[64][84]@26880 ; qtmp f32[64][100]@0
// epilogue overlay: cacc0 f32[64][84]@0 ; cacc1 f32[64][84]@21504 (ends 43008)
#define SMEM_BYTES 62992

__device__ __forceinline__ float E2(float x) { return __builtin_amdgcn_exp2f(x); }
// f32x2 -> f16x2 (RTZ, single v_cvt_pkrtz_f16_f32)
__device__ __forceinline__ unsigned pkh(float lo, float hi) {
  union { fp16x2 h; unsigned u; } cv;
  cv.h = __builtin_amdgcn_cvt_pkrtz(lo, hi);
  return cv.u;
}

// 16x16 K=32 f16 MFMA. C/D: col=lane&15, row=4*(lane>>4)+r (dtype-independent).
// A and B share the (lane-group g, reg-slot j) -> k=8g+j map (verified R2-R11).
__device__ __forceinline__ f32x4 mfma16f(f16x8 a, f16x8 b, f32x4 c) {
  return __builtin_amdgcn_mfma_f32_16x16x32_f16(a, b, c, 0, 0, 0);
}

// Pin EXACTLY 4 waves/SIMD: VGPR budget 128, forbids the 64-VGPR/8-wave
// allocation the compiler chose in R12 (10 MB/dispatch scratch spills).
__global__ __attribute__((amdgpu_flat_work_group_size(NTHREADS, NTHREADS),
                          amdgpu_waves_per_eu(4, 4)))
void DecoderAttention_62989990363717_kernel(const float* __restrict__ enc,
                                            const float* __restrict__ dec,
                                            const int* __restrict__ maskp,
                                            const float* __restrict__ W,
                                            float* __restrict__ out)
{
  __shared__ __align__(16) char smem[SMEM_BYTES];

  u16* ehP    = (u16*)smem;               // [2][12672]
  float* mbias = (float*)(smem + 50688);  // [2048]
  float* mst  = (float*)(smem + 58880);   // [8][64]
  float* lst  = (float*)(smem + 60928);   // [8][64]
  int* modep  = (int*)(smem + 62976);

  const int tid  = (int)threadIdx.x;
  const int lane = tid & 63;
  const int wv   = tid >> 6;    // 0..15
  const int sq   = wv >> 1;     // 16-row s-slice within tile: [16*sq, 16*sq+16)
  const int ph   = wv & 1;      // p-half: p in [32*ph, 32*ph+32), blocks {2ph, 2ph+1}
  const int l15  = lane & 15;
  const int g    = lane >> 4;
  const int b    = (int)blockIdx.x;

  const float* encB = enc + (size_t)b * NS * ND;
  const float* decB = dec + (size_t)b * NP * ND;

  // ---------- prologue: W, dec(scaled) -> LDS; mask->bias; Q ----------
  {
    float* Wl = (float*)smem;            // [80][84]
    float* dl = (float*)(smem + 26880);  // [64][84]
    for (int i = tid; i < 80 * 80; i += NTHREADS) Wl[(i / 80) * 84 + (i % 80)] = W[i];
    for (int i = tid; i < 64 * 80; i += NTHREADS)
      dl[(i / 80) * 84 + (i % 80)] = decB[i] * LOG2E;   // exp2-domain scores
    if (tid == 0) {
      const unsigned* mw = (const unsigned*)maskp;
      int ok = 1;
      for (int i = 0; i < 16; ++i) ok &= (mw[i] <= 1u);
      *modep = ok;   // 1 => int32 mask, 0 => int8 mask
    }
    __syncthreads();
    const int m32 = *modep;
    if (m32) {
      int v0 = maskp[(size_t)b * NS + tid];
      int v1 = maskp[(size_t)b * NS + tid + 1024];
      mbias[tid]        = v0 ? -3.0e38f : 0.0f;
      mbias[tid + 1024] = v1 ? -3.0e38f : 0.0f;
    } else if (tid < 512) {
      unsigned w = ((const unsigned*)maskp)[(size_t)b * (NS / 4) + tid];
      f32x4 bb;
      bb[0] = (w & 255u)         ? -3.0e38f : 0.0f;
      bb[1] = ((w >> 8) & 255u)  ? -3.0e38f : 0.0f;
      bb[2] = ((w >> 16) & 255u) ? -3.0e38f : 0.0f;
      bb[3] = (w >> 24)          ? -3.0e38f : 0.0f;
      *(f32x4*)&mbias[4 * tid] = bb;
    }
    // Q = dec @ W^T in fp32 (all 1024 threads: p = tid&63, e-range = 5*qw)
    float qa[5];
    const int qp = tid & 63, qw = tid >> 6;   // qw 0..15
#pragma unroll
    for (int j = 0; j < 5; ++j) qa[j] = 0.f;
    for (int kg = 0; kg < 20; ++kg) {
      f32x4 dv = *(const f32x4*)&dl[qp * 84 + kg * 4];
#pragma unroll
      for (int j = 0; j < 5; ++j) {
        f32x4 wv4 = *(const f32x4*)&Wl[(qw * 5 + j) * 84 + kg * 4];
        qa[j] = fmaf(dv.x, wv4.x, qa[j]);
        qa[j] = fmaf(dv.y, wv4.y, qa[j]);
        qa[j] = fmaf(dv.z, wv4.z, qa[j]);
        qa[j] = fmaf(dv.w, wv4.w, qa[j]);
      }
    }
    __syncthreads();            // Wl/dl reads done
    float* qtmp = (float*)smem; // [64][100], zeros at d=80..95
#pragma unroll
    for (int j = 0; j < 5; ++j) qtmp[qp * 100 + qw * 5 + j] = qa[j];
    if (qw == 15) {
#pragma unroll
      for (int z = 0; z < 16; ++z) qtmp[qp * 100 + 80 + z] = 0.f;
    }
    __syncthreads();
  }

  // ---------- Q fragments (persistent, single f16 RNE, 2 p-blocks) ----------
  f16x8 qb[2][3];
  {
    const float* qtmp = (const float*)smem;
#pragma unroll
    for (int pb = 0; pb < 2; ++pb) {
      const int prow = 32 * ph + 16 * pb + l15;
#pragma unroll
      for (int kk = 0; kk < 3; ++kk) {
        const int d0 = kk * 32 + g * 8;
        f32x4 f0 = *(const f32x4*)&qtmp[prow * 100 + d0];
        f32x4 f1 = *(const f32x4*)&qtmp[prow * 100 + d0 + 4];
        union { _Float16 h[8]; f16x8 v; } H;
        H.h[0] = (_Float16)f0.x; H.h[1] = (_Float16)f0.y;
        H.h[2] = (_Float16)f0.z; H.h[3] = (_Float16)f0.w;
        H.h[4] = (_Float16)f1.x; H.h[5] = (_Float16)f1.y;
        H.h[6] = (_Float16)f1.z; H.h[7] = (_Float16)f1.w;
        qb[pb][kk] = H.v;
      }
    }
  }
  __syncthreads();   // qtmp dead; staging may overwrite

  // ---------- zero K-pad regions (n=5) once: both buffers, 8 quarters ----------
  if (tid < 256) {
    const int buf = tid >> 7, q = (tid >> 4) & 7, row = tid & 15;
    u16* p = ehP + buf * BUFU + (q * 6 + 5) * 264 + row * 16;
    *(uint4*)p = make_uint4(0u, 0u, 0u, 0u);
    *(uint4*)(p + 8) = make_uint4(0u, 0u, 0u, 0u);
  }

  // loader roles: tid<640 stage enc (5 threads/row, 16 f32 each, all-b128 writes)
  const bool ldr = (tid < 640);
  const int srow = tid / 5;                 // 0..127
  const int c    = tid - srow * 5;          // 0..4 (d-block of 16)
  u16* ePW = ehP + ((srow >> 4) * 6 + c) * 264 + (srow & 15) * 16;
  const float* gsrc = encB + srow * ND + 16 * c;

#define STAGE_WRITE(bi)                                                          \
  do {                                                                           \
    if (ldr) {                                                                   \
      unsigned hh[8];                                                            \
      hh[0] = pkh(r0.x, r0.y); hh[1] = pkh(r0.z, r0.w);                          \
      hh[2] = pkh(r1.x, r1.y); hh[3] = pkh(r1.z, r1.w);                          \
      hh[4] = pkh(r2.x, r2.y); hh[5] = pkh(r2.z, r2.w);                          \
      hh[6] = pkh(r3.x, r3.y); hh[7] = pkh(r3.z, r3.w);                          \
      u16* a_ = ePW + (bi) * BUFU;                                               \
      *(uint4*)a_       = make_uint4(hh[0], hh[1], hh[2], hh[3]);                \
      *(uint4*)(a_ + 8) = make_uint4(hh[4], hh[5], hh[6], hh[7]);                \
    }                                                                            \
  } while (0)

  // ---------- stage tile 0 ----------
  {
    f32x4 r0, r1, r2, r3;
    if (ldr) {
      r0 = *(const f32x4*)gsrc;       r1 = *(const f32x4*)(gsrc + 4);
      r2 = *(const f32x4*)(gsrc + 8); r3 = *(const f32x4*)(gsrc + 12);
    }
    STAGE_WRITE(0);
    __syncthreads();
  }

  // ---------- main loop ----------
  f32x4 ctx0[5], ctx1[5];
#pragma unroll
  for (int n = 0; n < 5; ++n) { ctx0[n] = (f32x4){0.f,0.f,0.f,0.f}; ctx1[n] = (f32x4){0.f,0.f,0.f,0.f}; }
  // mr init -1e30 (NOT -3e38): masked rows give sv=-3e38 -> E2(sv-mr)=0 even
  // before any real max is seen (fully-masked-first-tile safety).
  float mr0 = -1.0e30f, mr1 = -1.0e30f, lr0 = 0.f, lr1 = 0.f;

  // QK A-frag base (u16 idx): region(sq, (g>>1)+2kk) + 16*l15 + 8*(g&1)
  //   -> element d = 32kk + 8g + j  (matches qb slot map); kk step = 528 u16
  const int qkOff = sq * 1584 + (g >> 1) * 264 + 16 * l15 + 8 * (g & 1);
  // PV tr-read base (bytes): region(sq, n) + 8*lane; n-step = 528 B
  const unsigned trBase = (unsigned)(uintptr_t)ehP + (unsigned)(sq * 3168 + 8 * lane);

  for (int tt = 0; tt < NTILE; ++tt) {
    const int cur = tt & 1, nxt = cur ^ 1;
    const bool hn = (tt + 1 < NTILE);
    f32x4 r0, r1, r2, r3;
    if (hn && ldr) {   // issue next-tile loads early (consumed at STAGE_WRITE)
      const float* src = gsrc + (size_t)(tt + 1) * STILE * ND;
      r0 = *(const f32x4*)src;       r1 = *(const f32x4*)(src + 4);
      r2 = *(const f32x4*)(src + 8); r3 = *(const f32x4*)(src + 12);
    }

    // ---- QK^T (swapped): one 16-row block x 2 p-blocks; E-frags SHARED ----
    f32x4 a0 = (f32x4){0.f, 0.f, 0.f, 0.f}, a1 = (f32x4){0.f, 0.f, 0.f, 0.f};
    {
      const u16* baseH = ehP + cur * BUFU + qkOff;
      f16x8 e0 = *(const f16x8*)(const void*)(baseH);
      f16x8 e1 = *(const f16x8*)(const void*)(baseH + 528);
      f16x8 e2 = *(const f16x8*)(const void*)(baseH + 1056);
      a0 = mfma16f(e0, qb[0][0], a0);
      a1 = mfma16f(e0, qb[1][0], a1);
      a0 = mfma16f(e1, qb[0][1], a0);
      a1 = mfma16f(e1, qb[1][1], a1);
      a0 = mfma16f(e2, qb[0][2], a0);
      a1 = mfma16f(e2, qb[1][2], a1);
    }

    // ---- masked online softmax over 16 rows x 32 p (exp2 domain), defer-max ----
    f32x4 bias4 = *(const f32x4*)&mbias[tt * 128 + 16 * sq + 4 * g];
    float sv0[4], sv1[4];
#pragma unroll
    for (int rr = 0; rr < 4; ++rr) {
      sv0[rr] = a0[rr] + bias4[rr];
      sv1[rr] = a1[rr] + bias4[rr];
    }
    float tm0 = fmaxf(fmaxf(sv0[0], sv0[1]), fmaxf(sv0[2], sv0[3]));
    tm0 = fmaxf(tm0, __shfl_xor(tm0, 16));
    tm0 = fmaxf(tm0, __shfl_xor(tm0, 32));
    float tm1 = fmaxf(fmaxf(sv1[0], sv1[1]), fmaxf(sv1[2], sv1[3]));
    tm1 = fmaxf(tm1, __shfl_xor(tm1, 16));
    tm1 = fmaxf(tm1, __shfl_xor(tm1, 32));
    const bool need = !__all((tm0 <= mr0 + 11.541560f) && (tm1 <= mr1 + 11.541560f));
    if (need) {
      float mn0 = fmaxf(mr0, tm0), mn1 = fmaxf(mr1, tm1);
      float esc0 = E2(mr0 - mn0), esc1 = E2(mr1 - mn1);
      lr0 *= esc0; lr1 *= esc1;
      mr0 = mn0; mr1 = mn1;
      float fr0[4], fr1[4];
#pragma unroll
      for (int rr = 0; rr < 4; ++rr) {
        fr0[rr] = __shfl(esc0, 4 * g + rr);
        fr1[rr] = __shfl(esc1, 4 * g + rr);
      }
#pragma unroll
      for (int n = 0; n < 5; ++n) {
#pragma unroll
        for (int rr = 0; rr < 4; ++rr) { ctx0[n][rr] *= fr0[rr]; ctx1[n][rr] *= fr1[rr]; }
      }
    }
    float p0[4], p1[4];
#pragma unroll
    for (int rr = 0; rr < 4; ++rr) {
      p0[rr] = E2(sv0[rr] - mr0);
      p1[rr] = E2(sv1[rr] - mr1);
    }
    lr0 += (p0[0] + p0[1]) + (p0[2] + p0[3]);
    lr1 += (p1[0] + p1[1]) + (p1[2] + p1[3]);

    // ---- PV: half-K=16 MFMA (slots 4..7 zero both sides, R7-verified).
    //      A: slot j = P[s=4g+j][p=l15 of pb]. B: tr-read(n) delivers
    //      E[s=4g+j][d=16n+l15] into slot j; B SHARED across p-blocks. ----
    union { unsigned uu[4]; f16x8 v; } PA0, PA1;
    PA0.uu[0] = pkh(p0[0], p0[1]); PA0.uu[1] = pkh(p0[2], p0[3]);
    PA0.uu[2] = 0u; PA0.uu[3] = 0u;
    PA1.uu[0] = pkh(p1[0], p1[1]); PA1.uu[1] = pkh(p1[2], p1[3]);
    PA1.uu[2] = 0u; PA1.uu[3] = 0u;
    const unsigned tra = trBase + (unsigned)(cur * BUFBY);
    u16x4 tv0, tv1, tv2, tv3, tv4;
    asm volatile("ds_read_b64_tr_b16 %0, %1"             : "=v"(tv0) : "v"(tra));
    asm volatile("ds_read_b64_tr_b16 %0, %1 offset:528"  : "=v"(tv1) : "v"(tra));
    asm volatile("ds_read_b64_tr_b16 %0, %1 offset:1056" : "=v"(tv2) : "v"(tra));
    asm volatile("ds_read_b64_tr_b16 %0, %1 offset:1584" : "=v"(tv3) : "v"(tra));
    asm volatile("ds_read_b64_tr_b16 %0, %1 offset:2112" : "=v"(tv4) : "v"(tra));
    asm volatile("s_waitcnt lgkmcnt(0)" ::: "memory");
    __builtin_amdgcn_sched_barrier(0);
#define PVN(n, tvn)                                                              \
    {                                                                            \
      union { u16 s[8]; f16x8 v; } B_;                                           \
      B_.s[0] = (tvn)[0]; B_.s[1] = (tvn)[1];                                    \
      B_.s[2] = (tvn)[2]; B_.s[3] = (tvn)[3];                                    \
      B_.s[4] = 0; B_.s[5] = 0; B_.s[6] = 0; B_.s[7] = 0;                        \
      ctx0[n] = mfma16f(PA0.v, B_.v, ctx0[n]);                                   \
      ctx1[n] = mfma16f(PA1.v, B_.v, ctx1[n]);                                   \
    }
    PVN(0, tv0) PVN(1, tv1) PVN(2, tv2) PVN(3, tv3) PVN(4, tv4)
#undef PVN

    if (hn) { STAGE_WRITE(nxt); }
    __syncthreads();
  }

  // ---------- epilogue: reduce lr, merge 8 s-slices, normalize, write ----------
  lr0 += __shfl_xor(lr0, 16); lr0 += __shfl_xor(lr0, 32);
  lr1 += __shfl_xor(lr1, 16); lr1 += __shfl_xor(lr1, 32);
  if (g == 0) {
    const int pi = 32 * ph + l15;
    mst[sq * 64 + pi] = mr0;      lst[sq * 64 + pi] = lr0;
    mst[sq * 64 + pi + 16] = mr1; lst[sq * 64 + pi + 16] = lr1;
  }
  __syncthreads();
  float F0, F1;
  {
    const int p0i = 32 * ph + l15, p1i = p0i + 16;
    float M0 = mst[p0i], M1 = mst[p1i];
#pragma unroll
    for (int k = 1; k < 8; ++k) {
      M0 = fmaxf(M0, mst[k * 64 + p0i]);
      M1 = fmaxf(M1, mst[k * 64 + p1i]);
    }
    F0 = E2(mr0 - M0); F1 = E2(mr1 - M1);
  }
  float g0[4], g1[4];
#pragma unroll
  for (int rr = 0; rr < 4; ++rr) {
    g0[rr] = __shfl(F0, 4 * g + rr);
    g1[rr] = __shfl(F1, 4 * g + rr);
  }
  float* cacc0 = (float*)smem;            // [64][84] (buffers dead after loop barrier)
  float* cacc1 = (float*)(smem + 21504);  // [64][84]
  for (int qq = 0; qq < 8; qq += 2) {
    if (sq == qq) {
#pragma unroll
      for (int n = 0; n < 5; ++n) {
#pragma unroll
        for (int rr = 0; rr < 4; ++rr) {
          const int r0_ = 32 * ph + 4 * g + rr;
          const int col = 16 * n + l15;
          float v0 = ctx0[n][rr] * g0[rr];
          float v1 = ctx1[n][rr] * g1[rr];
          if (qq == 0) { cacc0[r0_ * 84 + col] = v0; cacc0[(r0_ + 16) * 84 + col] = v1; }
          else         { cacc0[r0_ * 84 + col] += v0; cacc0[(r0_ + 16) * 84 + col] += v1; }
        }
      }
    }
    if (sq == qq + 1) {
#pragma unroll
      for (int n = 0; n < 5; ++n) {
#pragma unroll
        for (int rr = 0; rr < 4; ++rr) {
          const int r0_ = 32 * ph + 4 * g + rr;
          const int col = 16 * n + l15;
          float v0 = ctx0[n][rr] * g0[rr];
          float v1 = ctx1[n][rr] * g1[rr];
          if (qq == 0) { cacc1[r0_ * 84 + col] = v0; cacc1[(r0_ + 16) * 84 + col] = v1; }
          else         { cacc1[r0_ * 84 + col] += v0; cacc1[(r0_ + 16) * 84 + col] += v1; }
        }
      }
    }
    __syncthreads();
  }
  {
    const int op = tid >> 4, oc = tid & 15, od0 = oc * 5;
    float Mv = mst[op];
#pragma unroll
    for (int k = 1; k < 8; ++k) Mv = fmaxf(Mv, mst[k * 64 + op]);
    float Lv = 0.f;
#pragma unroll
    for (int k = 0; k < 8; ++k) Lv += lst[k * 64 + op] * E2(mst[k * 64 + op] - Mv);
    float inv = 1.0f / Lv;
    float* orow = out + ((size_t)b * NP + op) * ND + od0;
    const float* c0 = cacc0 + op * 84 + od0;
    const float* c1 = cacc1 + op * 84 + od0;
#pragma unroll
    for (int i = 0; i < 5; ++i) orow[i] = (c0[i] + c1[i]) * inv;
  }
}

extern "C" void kernel_launch(void* const* d_in, const int* in_sizes, int n_in,
                              void* d_out, int out_size, void* d_ws, size_t ws_size,
                              hipStream_t stream) {
  (void)in_sizes; (void)n_in; (void)out_size; (void)d_ws; (void)ws_size;
  const float* enc  = (const float*)d_in[0];
  const float* dec  = (const float*)d_in[1];
  const int*   mask = (const int*)d_in[2];
  const float* W    = (const float*)d_in[3];
  float* out = (float*)d_out;
  DecoderAttention_62989990363717_kernel<<<dim3(NB), dim3(NTHREADS), 0, stream>>>(
      enc, dec, mask, W, out);
}

// Round 14
// 40.226 us; speedup vs baseline: 1.7299x; 1.7299x over previous
//
#include <hip/hip_runtime.h>

#define NB 256
#define NS 2048
#define NP 64
#define ND 80
#define STILE 128
#define NTILE 16            // NS/STILE
#define NTHREADS 1024
#define LOG2E 1.4426950408889634f

typedef __attribute__((ext_vector_type(4))) float f32x4;
typedef __attribute__((ext_vector_type(2))) __fp16 fp16x2;
typedef __attribute__((ext_vector_type(8))) _Float16 f16x8;
typedef __attribute__((ext_vector_type(4))) unsigned short u16x4;
typedef unsigned short u16;

// ---------------- LDS layout (bytes) ----------------
// ehP  u16[2][8][6][264] @ 0     (50688)  f16 enc, 16x16 [s][d] row-major regions;
//        region(q,n), q = s>>4 (8 quarters of 128-row tile), n = d-block (n=5 = K-pad,
//        zeroed once). Region stride 264 u16 (=528B); per-buf stride 12672 u16.
// mbias f32[2048]        @ 50688 (8192)   0.0 / -3e38 per s (mask preconverted)
// mst  f32[4][64] @ 58880 ; lst f32[4][64] @ 59904 ; modep @ 60928
// prologue overlay: W f32[80][84]@0 ; dec f32[64][84]@26880 ; qtmp f32[64][100]@0
// epilogue overlay: cacc f32[64][84]@0
#define SMEM_BYTES 60944

__device__ __forceinline__ float E2(float x) { return __builtin_amdgcn_exp2f(x); }
// f32x2 -> f16x2 (RTZ, single v_cvt_pkrtz_f16_f32)
__device__ __forceinline__ unsigned pkh(float lo, float hi) {
  union { fp16x2 h; unsigned u; } cv;
  cv.h = __builtin_amdgcn_cvt_pkrtz(lo, hi);
  return cv.u;
}

// 16x16 K=32 f16 MFMA. C/D: col=lane&15, row=4*(lane>>4)+r (dtype-independent).
// A and B share the (lane-group g, reg-slot j) -> k=8g+j map (verified R2-R10).
__device__ __forceinline__ f32x4 mfma16f(f16x8 a, f16x8 b, f32x4 c) {
  return __builtin_amdgcn_mfma_f32_16x16x32_f16(a, b, c, 0, 0, 0);
}

// R10 shape (verified 40.5us, no spill). R12/R13's shared-operand shape spilled
// (VGPR=64 + 10-19MB scratch) — do NOT double per-thread ctx/Q state.
__global__ __launch_bounds__(NTHREADS, 4)
void DecoderAttention_62989990363717_kernel(const float* __restrict__ enc,
                                            const float* __restrict__ dec,
                                            const int* __restrict__ maskp,
                                            const float* __restrict__ W,
                                            float* __restrict__ out)
{
  __shared__ __align__(16) char smem[SMEM_BYTES];

  u16* ehP    = (u16*)smem;               // [2][12672]
  float* mbias = (float*)(smem + 50688);  // [2048]
  float* mst  = (float*)(smem + 58880);   // [4][64]
  float* lst  = (float*)(smem + 59904);   // [4][64]
  int* modep  = (int*)(smem + 60928);

  const int tid  = (int)threadIdx.x;
  const int lane = tid & 63;
  const int wv   = tid >> 6;    // 0..15
  const int pp   = wv & 3;      // p-block: rows [16*pp, 16*pp+16)
  const int sq   = wv >> 2;     // 32-row s-slice within tile: quarters {2sq, 2sq+1}
  const int l15  = lane & 15;
  const int g    = lane >> 4;
  const int b    = (int)blockIdx.x;

  const float* encB = enc + (size_t)b * NS * ND;
  const float* decB = dec + (size_t)b * NP * ND;

  // ---------- prologue: W, dec(scaled) -> LDS; mask->bias; Q ----------
  {
    float* Wl = (float*)smem;            // [80][84]
    float* dl = (float*)(smem + 26880);  // [64][84]
    for (int i = tid; i < 80 * 80; i += NTHREADS) Wl[(i / 80) * 84 + (i % 80)] = W[i];
    for (int i = tid; i < 64 * 80; i += NTHREADS)
      dl[(i / 80) * 84 + (i % 80)] = decB[i] * LOG2E;   // exp2-domain scores
    if (tid == 0) {
      const unsigned* mw = (const unsigned*)maskp;
      int ok = 1;
      for (int i = 0; i < 16; ++i) ok &= (mw[i] <= 1u);
      *modep = ok;   // 1 => int32 mask, 0 => int8 mask
    }
    __syncthreads();
    const int m32 = *modep;
    if (m32) {
      int v0 = maskp[(size_t)b * NS + tid];
      int v1 = maskp[(size_t)b * NS + tid + 1024];
      mbias[tid]        = v0 ? -3.0e38f : 0.0f;
      mbias[tid + 1024] = v1 ? -3.0e38f : 0.0f;
    } else if (tid < 512) {
      unsigned w = ((const unsigned*)maskp)[(size_t)b * (NS / 4) + tid];
      f32x4 bb;
      bb[0] = (w & 255u)         ? -3.0e38f : 0.0f;
      bb[1] = ((w >> 8) & 255u)  ? -3.0e38f : 0.0f;
      bb[2] = ((w >> 16) & 255u) ? -3.0e38f : 0.0f;
      bb[3] = (w >> 24)          ? -3.0e38f : 0.0f;
      *(f32x4*)&mbias[4 * tid] = bb;
    }
    // Q = dec @ W^T in fp32 (all 1024 threads: p = tid&63, e-range = 5*qw)
    float qa[5];
    const int qp = tid & 63, qw = tid >> 6;   // qw 0..15
#pragma unroll
    for (int j = 0; j < 5; ++j) qa[j] = 0.f;
    for (int kg = 0; kg < 20; ++kg) {
      f32x4 dv = *(const f32x4*)&dl[qp * 84 + kg * 4];
#pragma unroll
      for (int j = 0; j < 5; ++j) {
        f32x4 wv4 = *(const f32x4*)&Wl[(qw * 5 + j) * 84 + kg * 4];
        qa[j] = fmaf(dv.x, wv4.x, qa[j]);
        qa[j] = fmaf(dv.y, wv4.y, qa[j]);
        qa[j] = fmaf(dv.z, wv4.z, qa[j]);
        qa[j] = fmaf(dv.w, wv4.w, qa[j]);
      }
    }
    __syncthreads();            // Wl/dl reads done
    float* qtmp = (float*)smem; // [64][100], zeros at d=80..95
#pragma unroll
    for (int j = 0; j < 5; ++j) qtmp[qp * 100 + qw * 5 + j] = qa[j];
    if (qw == 15) {
#pragma unroll
      for (int z = 0; z < 16; ++z) qtmp[qp * 100 + 80 + z] = 0.f;
    }
    __syncthreads();
  }

  // ---------- Q fragments (persistent, single f16 RNE — no residual) ----------
  f16x8 qb[3];
  {
    const float* qtmp = (const float*)smem;
    const int prow = 16 * pp + l15;
#pragma unroll
    for (int kk = 0; kk < 3; ++kk) {
      const int d0 = kk * 32 + g * 8;
      f32x4 f0 = *(const f32x4*)&qtmp[prow * 100 + d0];
      f32x4 f1 = *(const f32x4*)&qtmp[prow * 100 + d0 + 4];
      union { _Float16 h[8]; f16x8 v; } H;
      H.h[0] = (_Float16)f0.x; H.h[1] = (_Float16)f0.y;
      H.h[2] = (_Float16)f0.z; H.h[3] = (_Float16)f0.w;
      H.h[4] = (_Float16)f1.x; H.h[5] = (_Float16)f1.y;
      H.h[6] = (_Float16)f1.z; H.h[7] = (_Float16)f1.w;
      qb[kk] = H.v;
    }
  }
  __syncthreads();   // qtmp dead; staging may overwrite

  // ---------- zero K-pad regions (n=5) once: both buffers, 8 quarters ----------
  if (tid < 256) {
    const int buf = tid >> 7, q = (tid >> 4) & 7, row = tid & 15;
    u16* p = ehP + buf * 12672 + (q * 6 + 5) * 264 + row * 16;
    *(uint4*)p = make_uint4(0u, 0u, 0u, 0u);
    *(uint4*)(p + 8) = make_uint4(0u, 0u, 0u, 0u);
  }

  // loader roles: tid<640 stage enc (5 threads/row, 16 f32 each, all-b128 writes)
  const bool ldr = (tid < 640);
  const int srow = tid / 5;                 // 0..127
  const int c    = tid - srow * 5;          // 0..4 (d-block of 16)
  u16* ePW = ehP + ((srow >> 4) * 6 + c) * 264 + (srow & 15) * 16;
  const float* gsrc = encB + srow * ND + 16 * c;

#define STAGE_WRITE(bi)                                                          \
  do {                                                                           \
    if (ldr) {                                                                   \
      unsigned hh[8];                                                            \
      hh[0] = pkh(r0.x, r0.y); hh[1] = pkh(r0.z, r0.w);                          \
      hh[2] = pkh(r1.x, r1.y); hh[3] = pkh(r1.z, r1.w);                          \
      hh[4] = pkh(r2.x, r2.y); hh[5] = pkh(r2.z, r2.w);                          \
      hh[6] = pkh(r3.x, r3.y); hh[7] = pkh(r3.z, r3.w);                          \
      u16* a_ = ePW + (bi) * 12672;                                              \
      *(uint4*)a_       = make_uint4(hh[0], hh[1], hh[2], hh[3]);                \
      *(uint4*)(a_ + 8) = make_uint4(hh[4], hh[5], hh[6], hh[7]);                \
    }                                                                            \
  } while (0)

  // ---------- stage tile 0 ----------
  {
    f32x4 r0, r1, r2, r3;
    if (ldr) {
      r0 = *(const f32x4*)gsrc;       r1 = *(const f32x4*)(gsrc + 4);
      r2 = *(const f32x4*)(gsrc + 8); r3 = *(const f32x4*)(gsrc + 12);
    }
    STAGE_WRITE(0);
    __syncthreads();
  }

  // ---------- main loop ----------
  f32x4 ctx[5];
#pragma unroll
  for (int n = 0; n < 5; ++n) ctx[n] = (f32x4){0.f, 0.f, 0.f, 0.f};
  // mr init -1e30 (NOT -3e38): masked rows give sv=-3e38 -> E2(sv-mr)=0 even
  // before any real max is seen (fully-masked-first-tile safety).
  float mr = -1.0e30f, lr = 0.f;   // lr: per-lane partial (reduced in epilogue)

  // QK A-frag base (u16 idx): region(2sq+blk, (g>>1)+2kk) + 16*l15 + 8*(g&1)
  //   -> element d = 32kk + 8g + j  (matches qb slot map)
  const int qkOff = (2 * sq) * 1584 + (g >> 1) * 264 + 16 * l15 + 8 * (g & 1);
  // PV tr-read base (bytes): region(2sq, n) + 8*lane; blk1 = +3168B, n-step = 528B
  const unsigned trBase = (unsigned)(uintptr_t)ehP + (unsigned)(sq * 6336 + 8 * lane);

  for (int tt = 0; tt < NTILE; ++tt) {
    const int cur = tt & 1, nxt = cur ^ 1;
    const bool hn = (tt + 1 < NTILE);
    f32x4 r0, r1, r2, r3;
    if (hn && ldr) {   // issue next-tile loads early (consumed at STAGE_WRITE)
      const float* src = gsrc + (size_t)(tt + 1) * STILE * ND;
      r0 = *(const f32x4*)src;       r1 = *(const f32x4*)(src + 4);
      r2 = *(const f32x4*)(src + 8); r3 = *(const f32x4*)(src + 12);
    }

    // ---- QK^T (swapped): two 16-row blocks, K=96, single-f16 Q ----
    f32x4 a0 = (f32x4){0.f, 0.f, 0.f, 0.f}, a1 = (f32x4){0.f, 0.f, 0.f, 0.f};
    {
      const u16* baseH0 = ehP + cur * 12672 + qkOff;
      const u16* baseH1 = baseH0 + 1584;
      f16x8 e0[3], e1[3];
#pragma unroll
      for (int kk = 0; kk < 3; ++kk) {
        e0[kk] = *(const f16x8*)(const void*)(baseH0 + kk * 528);
        e1[kk] = *(const f16x8*)(const void*)(baseH1 + kk * 528);
      }
#pragma unroll
      for (int kk = 0; kk < 3; ++kk) {
        a0 = mfma16f(e0[kk], qb[kk], a0);
        a1 = mfma16f(e1[kk], qb[kk], a1);
      }
    }

    // ---- masked online softmax over 32 rows (exp2 domain), defer-max ----
    const int mb0 = tt * 128 + 32 * sq + 4 * g;
    f32x4 bias0 = *(const f32x4*)&mbias[mb0];
    f32x4 bias1 = *(const f32x4*)&mbias[mb0 + 16];
    float sv0[4], sv1[4];
#pragma unroll
    for (int rr = 0; rr < 4; ++rr) {
      sv0[rr] = a0[rr] + bias0[rr];
      sv1[rr] = a1[rr] + bias1[rr];
    }
    float tm = fmaxf(fmaxf(fmaxf(sv0[0], sv0[1]), fmaxf(sv0[2], sv0[3])),
                     fmaxf(fmaxf(sv1[0], sv1[1]), fmaxf(sv1[2], sv1[3])));
    tm = fmaxf(tm, __shfl_xor(tm, 16));
    tm = fmaxf(tm, __shfl_xor(tm, 32));
    const bool need = !__all(tm <= mr + 11.541560f);   // 8 * log2(e)
    if (need) {
      float mn = fmaxf(mr, tm);
      float esc = E2(mr - mn);
      lr *= esc; mr = mn;
      float fr[4];
#pragma unroll
      for (int rr = 0; rr < 4; ++rr) fr[rr] = __shfl(esc, 4 * g + rr);
#pragma unroll
      for (int n = 0; n < 5; ++n) {
#pragma unroll
        for (int rr = 0; rr < 4; ++rr) ctx[n][rr] *= fr[rr];
      }
    }
    float p0[4], p1[4];
#pragma unroll
    for (int rr = 0; rr < 4; ++rr) {
      p0[rr] = E2(sv0[rr] - mr);
      p1[rr] = E2(sv1[rr] - mr);
    }
    lr += ((p0[0] + p0[1]) + (p0[2] + p0[3])) + ((p1[0] + p1[1]) + (p1[2] + p1[3]));

    // ---- PV: full-K=32 MFMA. A slots: j=0..3 <- blk0 rows 4g+j,
    //      j=4..7 <- blk1 rows 4g+j. B: tr-read(blk, n) delivers
    //      E_blk[4g+j][16n+l15] into slots 4*blk+j — same k->s map. ----
    union { unsigned uu[4]; f16x8 v; } PA;
    PA.uu[0] = pkh(p0[0], p0[1]); PA.uu[1] = pkh(p0[2], p0[3]);
    PA.uu[2] = pkh(p1[0], p1[1]); PA.uu[3] = pkh(p1[2], p1[3]);
    const unsigned tra = trBase + (unsigned)(cur * 25344);
    {
      u16x4 ta0, tb0, ta1, tb1, ta2, tb2;
      asm volatile("ds_read_b64_tr_b16 %0, %1"             : "=v"(ta0) : "v"(tra));
      asm volatile("ds_read_b64_tr_b16 %0, %1 offset:3168" : "=v"(tb0) : "v"(tra));
      asm volatile("ds_read_b64_tr_b16 %0, %1 offset:528"  : "=v"(ta1) : "v"(tra));
      asm volatile("ds_read_b64_tr_b16 %0, %1 offset:3696" : "=v"(tb1) : "v"(tra));
      asm volatile("ds_read_b64_tr_b16 %0, %1 offset:1056" : "=v"(ta2) : "v"(tra));
      asm volatile("ds_read_b64_tr_b16 %0, %1 offset:4224" : "=v"(tb2) : "v"(tra));
      asm volatile("s_waitcnt lgkmcnt(0)" ::: "memory");
      __builtin_amdgcn_sched_barrier(0);
      union { u16 s[8]; f16x8 v; } B0, B1, B2;
#pragma unroll
      for (int j = 0; j < 4; ++j) {
        B0.s[j] = ta0[j]; B0.s[4 + j] = tb0[j];
        B1.s[j] = ta1[j]; B1.s[4 + j] = tb1[j];
        B2.s[j] = ta2[j]; B2.s[4 + j] = tb2[j];
      }
      ctx[0] = mfma16f(PA.v, B0.v, ctx[0]);
      ctx[1] = mfma16f(PA.v, B1.v, ctx[1]);
      ctx[2] = mfma16f(PA.v, B2.v, ctx[2]);
    }
    {
      u16x4 ta3, tb3, ta4, tb4;
      asm volatile("ds_read_b64_tr_b16 %0, %1 offset:1584" : "=v"(ta3) : "v"(tra));
      asm volatile("ds_read_b64_tr_b16 %0, %1 offset:4752" : "=v"(tb3) : "v"(tra));
      asm volatile("ds_read_b64_tr_b16 %0, %1 offset:2112" : "=v"(ta4) : "v"(tra));
      asm volatile("ds_read_b64_tr_b16 %0, %1 offset:5280" : "=v"(tb4) : "v"(tra));
      asm volatile("s_waitcnt lgkmcnt(0)" ::: "memory");
      __builtin_amdgcn_sched_barrier(0);
      union { u16 s[8]; f16x8 v; } B3, B4;
#pragma unroll
      for (int j = 0; j < 4; ++j) {
        B3.s[j] = ta3[j]; B3.s[4 + j] = tb3[j];
        B4.s[j] = ta4[j]; B4.s[4 + j] = tb4[j];
      }
      ctx[3] = mfma16f(PA.v, B3.v, ctx[3]);
      ctx[4] = mfma16f(PA.v, B4.v, ctx[4]);
    }

    if (hn) { STAGE_WRITE(nxt); }
    __syncthreads();
  }

  // ---------- epilogue: reduce lr, merge 4 s-slices, normalize, write ----------
  lr += __shfl_xor(lr, 16);
  lr += __shfl_xor(lr, 32);
  if (g == 0) {
    mst[sq * 64 + 16 * pp + l15] = mr;
    lst[sq * 64 + 16 * pp + l15] = lr;
  }
  __syncthreads();
  float F;
  {
    const int pi = 16 * pp + l15;
    float M = fmaxf(fmaxf(mst[pi], mst[64 + pi]), fmaxf(mst[128 + pi], mst[192 + pi]));
    F = E2(mr - M);
  }
  float gg[4];
#pragma unroll
  for (int rr = 0; rr < 4; ++rr) gg[rr] = __shfl(F, 4 * g + rr);
  float* cacc = (float*)smem;  // [64][84]
  for (int qq = 0; qq < 4; ++qq) {
    if (sq == qq) {
#pragma unroll
      for (int n = 0; n < 5; ++n) {
#pragma unroll
        for (int rr = 0; rr < 4; ++rr) {
          const int row = 16 * pp + 4 * g + rr;
          const int col = 16 * n + l15;
          float v = ctx[n][rr] * gg[rr];
          if (qq == 0) cacc[row * 84 + col] = v;
          else         cacc[row * 84 + col] += v;
        }
      }
    }
    __syncthreads();
  }
  {
    const int op = tid >> 4, oc = tid & 15;
    float Mv = fmaxf(fmaxf(mst[op], mst[64 + op]), fmaxf(mst[128 + op], mst[192 + op]));
    float Lv = lst[op] * E2(mst[op] - Mv) + lst[64 + op] * E2(mst[64 + op] - Mv)
             + lst[128 + op] * E2(mst[128 + op] - Mv) + lst[192 + op] * E2(mst[192 + op] - Mv);
    float inv = 1.0f / Lv;
    float* orow = out + ((size_t)b * NP + op) * ND + oc * 5;
    const float* crow = cacc + op * 84 + oc * 5;
#pragma unroll
    for (int i = 0; i < 5; ++i) orow[i] = crow[i] * inv;
  }
}

extern "C" void kernel_launch(void* const* d_in, const int* in_sizes, int n_in,
                              void* d_out, int out_size, void* d_ws, size_t ws_size,
                              hipStream_t stream) {
  (void)in_sizes; (void)n_in; (void)out_size; (void)d_ws; (void)ws_size;
  const float* enc  = (const float*)d_in[0];
  const float* dec  = (const float*)d_in[1];
  const int*   mask = (const int*)d_in[2];
  const float* W    = (const float*)d_in[3];
  float* out = (float*)d_out;
  DecoderAttention_62989990363717_kernel<<<dim3(NB), dim3(NTHREADS), 0, stream>>>(
      enc, dec, mask, W, out);
}

// Round 15
// 39.873 us; speedup vs baseline: 1.7452x; 1.0088x over previous
//
#include <hip/hip_runtime.h>

#define NB 256
#define NS 2048
#define NP 64
#define ND 80
#define STILE 128
#define NTILE 16            // NS/STILE
#define NTHREADS 1024
#define LOG2E 1.4426950408889634f

typedef __attribute__((ext_vector_type(4))) float f32x4;
typedef __attribute__((ext_vector_type(2))) __fp16 fp16x2;
typedef __attribute__((ext_vector_type(8))) _Float16 f16x8;
typedef __attribute__((ext_vector_type(4))) unsigned short u16x4;
typedef unsigned short u16;

// ---------------- LDS layout (bytes) ----------------
// ehP  u16[2][8][6][264] @ 0     (50688)  f16 enc, 16x16 [s][d] row-major regions;
//        region(q,n), q = s>>4 (8 quarters of 128-row tile), n = d-block (n=5 = K-pad,
//        zeroed once). Region stride 264 u16 (=528B); per-buf stride 12672 u16.
// mbias f32[2048]        @ 50688 (8192)   0.0 / -3e38 per s (mask preconverted)
// mst  f32[4][64] @ 58880 ; lst f32[4][64] @ 59904 ; modep @ 60928
// prologue overlay: W f32[80][84]@0 ; dec f32[64][84]@26880 ; qtmp f32[64][100]@0
// epilogue overlay: cacc f32[64][84]@0
#define SMEM_BYTES 60944

__device__ __forceinline__ float E2(float x) { return __builtin_amdgcn_exp2f(x); }
// f32x2 -> f16x2 (RTZ, single v_cvt_pkrtz_f16_f32)
__device__ __forceinline__ unsigned pkh(float lo, float hi) {
  union { fp16x2 h; unsigned u; } cv;
  cv.h = __builtin_amdgcn_cvt_pkrtz(lo, hi);
  return cv.u;
}

// 16x16 K=32 f16 MFMA. C/D: col=lane&15, row=4*(lane>>4)+r (dtype-independent).
// A and B share the (lane-group g, reg-slot j) -> k=8g+j map (verified R2-R14).
__device__ __forceinline__ f32x4 mfma16f(f16x8 a, f16x8 b, f32x4 c) {
  return __builtin_amdgcn_mfma_f32_16x16x32_f16(a, b, c, 0, 0, 0);
}

// R10/R14 shape (verified 40.2-40.5us, no spill). R12/R13's shared-operand shape
// spilled (VGPR=64 + 10-19MB scratch) — do NOT double per-thread ctx/Q state.
__global__ __launch_bounds__(NTHREADS, 4)
void DecoderAttention_62989990363717_kernel(const float* __restrict__ enc,
                                            const float* __restrict__ dec,
                                            const int* __restrict__ maskp,
                                            const float* __restrict__ W,
                                            float* __restrict__ out)
{
  __shared__ __align__(16) char smem[SMEM_BYTES];

  u16* ehP    = (u16*)smem;               // [2][12672]
  float* mbias = (float*)(smem + 50688);  // [2048]
  float* mst  = (float*)(smem + 58880);   // [4][64]
  float* lst  = (float*)(smem + 59904);   // [4][64]
  int* modep  = (int*)(smem + 60928);

  const int tid  = (int)threadIdx.x;
  const int lane = tid & 63;
  const int wv   = tid >> 6;    // 0..15
  const int pp   = wv & 3;      // p-block: rows [16*pp, 16*pp+16)
  const int sq   = wv >> 2;     // 32-row s-slice within tile: quarters {2sq, 2sq+1}
  const int l15  = lane & 15;
  const int g    = lane >> 4;
  const int b    = (int)blockIdx.x;

  const float* encB = enc + (size_t)b * NS * ND;
  const float* decB = dec + (size_t)b * NP * ND;

  // ---------- prologue: W, dec(scaled) -> LDS; mask->bias; Q ----------
  {
    float* Wl = (float*)smem;            // [80][84]
    float* dl = (float*)(smem + 26880);  // [64][84]
    for (int i = tid; i < 80 * 80; i += NTHREADS) Wl[(i / 80) * 84 + (i % 80)] = W[i];
    for (int i = tid; i < 64 * 80; i += NTHREADS)
      dl[(i / 80) * 84 + (i % 80)] = decB[i] * LOG2E;   // exp2-domain scores
    if (tid == 0) {
      const unsigned* mw = (const unsigned*)maskp;
      int ok = 1;
      for (int i = 0; i < 16; ++i) ok &= (mw[i] <= 1u);
      *modep = ok;   // 1 => int32 mask, 0 => int8 mask
    }
    __syncthreads();
    const int m32 = *modep;
    if (m32) {
      int v0 = maskp[(size_t)b * NS + tid];
      int v1 = maskp[(size_t)b * NS + tid + 1024];
      mbias[tid]        = v0 ? -3.0e38f : 0.0f;
      mbias[tid + 1024] = v1 ? -3.0e38f : 0.0f;
    } else if (tid < 512) {
      unsigned w = ((const unsigned*)maskp)[(size_t)b * (NS / 4) + tid];
      f32x4 bb;
      bb[0] = (w & 255u)         ? -3.0e38f : 0.0f;
      bb[1] = ((w >> 8) & 255u)  ? -3.0e38f : 0.0f;
      bb[2] = ((w >> 16) & 255u) ? -3.0e38f : 0.0f;
      bb[3] = (w >> 24)          ? -3.0e38f : 0.0f;
      *(f32x4*)&mbias[4 * tid] = bb;
    }
    // Q = dec @ W^T in fp32 (all 1024 threads: p = tid&63, e-range = 5*qw)
    float qa[5];
    const int qp = tid & 63, qw = tid >> 6;   // qw 0..15
#pragma unroll
    for (int j = 0; j < 5; ++j) qa[j] = 0.f;
    for (int kg = 0; kg < 20; ++kg) {
      f32x4 dv = *(const f32x4*)&dl[qp * 84 + kg * 4];
#pragma unroll
      for (int j = 0; j < 5; ++j) {
        f32x4 wv4 = *(const f32x4*)&Wl[(qw * 5 + j) * 84 + kg * 4];
        qa[j] = fmaf(dv.x, wv4.x, qa[j]);
        qa[j] = fmaf(dv.y, wv4.y, qa[j]);
        qa[j] = fmaf(dv.z, wv4.z, qa[j]);
        qa[j] = fmaf(dv.w, wv4.w, qa[j]);
      }
    }
    __syncthreads();            // Wl/dl reads done
    float* qtmp = (float*)smem; // [64][100], zeros at d=80..95
#pragma unroll
    for (int j = 0; j < 5; ++j) qtmp[qp * 100 + qw * 5 + j] = qa[j];
    if (qw == 15) {
#pragma unroll
      for (int z = 0; z < 16; ++z) qtmp[qp * 100 + 80 + z] = 0.f;
    }
    __syncthreads();
  }

  // ---------- Q fragments (persistent, single f16 RNE — no residual) ----------
  f16x8 qb[3];
  {
    const float* qtmp = (const float*)smem;
    const int prow = 16 * pp + l15;
#pragma unroll
    for (int kk = 0; kk < 3; ++kk) {
      const int d0 = kk * 32 + g * 8;
      f32x4 f0 = *(const f32x4*)&qtmp[prow * 100 + d0];
      f32x4 f1 = *(const f32x4*)&qtmp[prow * 100 + d0 + 4];
      union { _Float16 h[8]; f16x8 v; } H;
      H.h[0] = (_Float16)f0.x; H.h[1] = (_Float16)f0.y;
      H.h[2] = (_Float16)f0.z; H.h[3] = (_Float16)f0.w;
      H.h[4] = (_Float16)f1.x; H.h[5] = (_Float16)f1.y;
      H.h[6] = (_Float16)f1.z; H.h[7] = (_Float16)f1.w;
      qb[kk] = H.v;
    }
  }
  __syncthreads();   // qtmp dead; staging may overwrite

  // ---------- zero K-pad regions (n=5) once: both buffers, 8 quarters ----------
  if (tid < 256) {
    const int buf = tid >> 7, q = (tid >> 4) & 7, row = tid & 15;
    u16* p = ehP + buf * 12672 + (q * 6 + 5) * 264 + row * 16;
    *(uint4*)p = make_uint4(0u, 0u, 0u, 0u);
    *(uint4*)(p + 8) = make_uint4(0u, 0u, 0u, 0u);
  }

  // loader roles: tid<640 stage enc (5 threads/row, 16 f32 each, all-b128 writes)
  const bool ldr = (tid < 640);
  const int srow = tid / 5;                 // 0..127
  const int c    = tid - srow * 5;          // 0..4 (d-block of 16)
  u16* ePW = ehP + ((srow >> 4) * 6 + c) * 264 + (srow & 15) * 16;
  const float* gsrc = encB + srow * ND + 16 * c;

#define STAGE_WRITE(bi)                                                          \
  do {                                                                           \
    if (ldr) {                                                                   \
      unsigned hh[8];                                                            \
      hh[0] = pkh(r0.x, r0.y); hh[1] = pkh(r0.z, r0.w);                          \
      hh[2] = pkh(r1.x, r1.y); hh[3] = pkh(r1.z, r1.w);                          \
      hh[4] = pkh(r2.x, r2.y); hh[5] = pkh(r2.z, r2.w);                          \
      hh[6] = pkh(r3.x, r3.y); hh[7] = pkh(r3.z, r3.w);                          \
      u16* a_ = ePW + (bi) * 12672;                                              \
      *(uint4*)a_       = make_uint4(hh[0], hh[1], hh[2], hh[3]);                \
      *(uint4*)(a_ + 8) = make_uint4(hh[4], hh[5], hh[6], hh[7]);                \
    }                                                                            \
  } while (0)

  // ---------- stage tile 0 ----------
  {
    f32x4 r0, r1, r2, r3;
    if (ldr) {
      r0 = *(const f32x4*)gsrc;       r1 = *(const f32x4*)(gsrc + 4);
      r2 = *(const f32x4*)(gsrc + 8); r3 = *(const f32x4*)(gsrc + 12);
    }
    STAGE_WRITE(0);
    __syncthreads();
  }

  // ---------- main loop ----------
  f32x4 ctx[5];
#pragma unroll
  for (int n = 0; n < 5; ++n) ctx[n] = (f32x4){0.f, 0.f, 0.f, 0.f};
  // mr init -1e30 (NOT -3e38): masked rows give sv=-3e38 -> E2(sv-mr)=0 even
  // before any real max is seen (fully-masked-first-tile safety).
  float mr = -1.0e30f, lr = 0.f;   // lr: per-lane partial (reduced in epilogue)

  // QK A-frag base (u16 idx): region(2sq+blk, (g>>1)+2kk) + 16*l15 + 8*(g&1)
  //   -> element d = 32kk + 8g + j  (matches qb slot map)
  const int qkOff = (2 * sq) * 1584 + (g >> 1) * 264 + 16 * l15 + 8 * (g & 1);
  // PV tr-read base (bytes): region(2sq, n) + 8*lane; blk1 = +3168B, n-step = 528B
  const unsigned trBase = (unsigned)(uintptr_t)ehP + (unsigned)(sq * 6336 + 8 * lane);

  for (int tt = 0; tt < NTILE; ++tt) {
    const int cur = tt & 1, nxt = cur ^ 1;
    const bool hn = (tt + 1 < NTILE);
    f32x4 r0, r1, r2, r3;
    if (hn && ldr) {   // issue next-tile loads early (consumed at STAGE_WRITE)
      const float* src = gsrc + (size_t)(tt + 1) * STILE * ND;
      r0 = *(const f32x4*)src;       r1 = *(const f32x4*)(src + 4);
      r2 = *(const f32x4*)(src + 8); r3 = *(const f32x4*)(src + 12);
    }

    // ---- QK^T (swapped): two 16-row blocks, K=96, single-f16 Q ----
    f32x4 a0 = (f32x4){0.f, 0.f, 0.f, 0.f}, a1 = (f32x4){0.f, 0.f, 0.f, 0.f};
    {
      const u16* baseH0 = ehP + cur * 12672 + qkOff;
      const u16* baseH1 = baseH0 + 1584;
      f16x8 e0[3], e1[3];
#pragma unroll
      for (int kk = 0; kk < 3; ++kk) {
        e0[kk] = *(const f16x8*)(const void*)(baseH0 + kk * 528);
        e1[kk] = *(const f16x8*)(const void*)(baseH1 + kk * 528);
      }
#pragma unroll
      for (int kk = 0; kk < 3; ++kk) {
        a0 = mfma16f(e0[kk], qb[kk], a0);
        a1 = mfma16f(e1[kk], qb[kk], a1);
      }
    }

    // ---- hoist bias loads (LDS) before the tr-read burst ----
    const int mb0 = tt * 128 + 32 * sq + 4 * g;
    f32x4 bias0 = *(const f32x4*)&mbias[mb0];
    f32x4 bias1 = *(const f32x4*)&mbias[mb0 + 16];

    // ---- issue ALL 10 PV tr-reads NOW; latency hides under softmax VALU ----
    const unsigned tra = trBase + (unsigned)(cur * 25344);
    u16x4 ta0, tb0, ta1, tb1, ta2, tb2, ta3, tb3, ta4, tb4;
    asm volatile("ds_read_b64_tr_b16 %0, %1"             : "=v"(ta0) : "v"(tra));
    asm volatile("ds_read_b64_tr_b16 %0, %1 offset:3168" : "=v"(tb0) : "v"(tra));
    asm volatile("ds_read_b64_tr_b16 %0, %1 offset:528"  : "=v"(ta1) : "v"(tra));
    asm volatile("ds_read_b64_tr_b16 %0, %1 offset:3696" : "=v"(tb1) : "v"(tra));
    asm volatile("ds_read_b64_tr_b16 %0, %1 offset:1056" : "=v"(ta2) : "v"(tra));
    asm volatile("ds_read_b64_tr_b16 %0, %1 offset:4224" : "=v"(tb2) : "v"(tra));
    asm volatile("ds_read_b64_tr_b16 %0, %1 offset:1584" : "=v"(ta3) : "v"(tra));
    asm volatile("ds_read_b64_tr_b16 %0, %1 offset:4752" : "=v"(tb3) : "v"(tra));
    asm volatile("ds_read_b64_tr_b16 %0, %1 offset:2112" : "=v"(ta4) : "v"(tra));
    asm volatile("ds_read_b64_tr_b16 %0, %1 offset:5280" : "=v"(tb4) : "v"(tra));

    // ---- masked online softmax over 32 rows (exp2 domain), defer-max ----
    float sv0[4], sv1[4];
#pragma unroll
    for (int rr = 0; rr < 4; ++rr) {
      sv0[rr] = a0[rr] + bias0[rr];
      sv1[rr] = a1[rr] + bias1[rr];
    }
    float tm = fmaxf(fmaxf(fmaxf(sv0[0], sv0[1]), fmaxf(sv0[2], sv0[3])),
                     fmaxf(fmaxf(sv1[0], sv1[1]), fmaxf(sv1[2], sv1[3])));
    tm = fmaxf(tm, __shfl_xor(tm, 16));
    tm = fmaxf(tm, __shfl_xor(tm, 32));
    const bool need = !__all(tm <= mr + 11.541560f);   // 8 * log2(e)
    if (need) {
      float mn = fmaxf(mr, tm);
      float esc = E2(mr - mn);
      lr *= esc; mr = mn;
      float fr[4];
#pragma unroll
      for (int rr = 0; rr < 4; ++rr) fr[rr] = __shfl(esc, 4 * g + rr);
#pragma unroll
      for (int n = 0; n < 5; ++n) {
#pragma unroll
        for (int rr = 0; rr < 4; ++rr) ctx[n][rr] *= fr[rr];
      }
    }
    float p0[4], p1[4];
#pragma unroll
    for (int rr = 0; rr < 4; ++rr) {
      p0[rr] = E2(sv0[rr] - mr);
      p1[rr] = E2(sv1[rr] - mr);
    }
    lr += ((p0[0] + p0[1]) + (p0[2] + p0[3])) + ((p1[0] + p1[1]) + (p1[2] + p1[3]));

    // ---- PV: full-K=32 MFMA. A slots: j=0..3 <- blk0 rows 4g+j,
    //      j=4..7 <- blk1 rows 4g+j. B: tr-read(blk, n) delivers
    //      E_blk[4g+j][16n+l15] into slots 4*blk+j — same k->s map. ----
    union { unsigned uu[4]; f16x8 v; } PA;
    PA.uu[0] = pkh(p0[0], p0[1]); PA.uu[1] = pkh(p0[2], p0[3]);
    PA.uu[2] = pkh(p1[0], p1[1]); PA.uu[3] = pkh(p1[2], p1[3]);
    asm volatile("s_waitcnt lgkmcnt(0)" ::: "memory");
    __builtin_amdgcn_sched_barrier(0);
    {
      union { u16 s[8]; f16x8 v; } B0, B1, B2, B3, B4;
#pragma unroll
      for (int j = 0; j < 4; ++j) {
        B0.s[j] = ta0[j]; B0.s[4 + j] = tb0[j];
        B1.s[j] = ta1[j]; B1.s[4 + j] = tb1[j];
        B2.s[j] = ta2[j]; B2.s[4 + j] = tb2[j];
        B3.s[j] = ta3[j]; B3.s[4 + j] = tb3[j];
        B4.s[j] = ta4[j]; B4.s[4 + j] = tb4[j];
      }
      ctx[0] = mfma16f(PA.v, B0.v, ctx[0]);
      ctx[1] = mfma16f(PA.v, B1.v, ctx[1]);
      ctx[2] = mfma16f(PA.v, B2.v, ctx[2]);
      ctx[3] = mfma16f(PA.v, B3.v, ctx[3]);
      ctx[4] = mfma16f(PA.v, B4.v, ctx[4]);
    }

    if (hn) { STAGE_WRITE(nxt); }
    __syncthreads();
  }

  // ---------- epilogue: reduce lr, merge 4 s-slices, normalize, write ----------
  lr += __shfl_xor(lr, 16);
  lr += __shfl_xor(lr, 32);
  if (g == 0) {
    mst[sq * 64 + 16 * pp + l15] = mr;
    lst[sq * 64 + 16 * pp + l15] = lr;
  }
  __syncthreads();
  float F;
  {
    const int pi = 16 * pp + l15;
    float M = fmaxf(fmaxf(mst[pi], mst[64 + pi]), fmaxf(mst[128 + pi], mst[192 + pi]));
    F = E2(mr - M);
  }
  float gg[4];
#pragma unroll
  for (int rr = 0; rr < 4; ++rr) gg[rr] = __shfl(F, 4 * g + rr);
  float* cacc = (float*)smem;  // [64][84]
  for (int qq = 0; qq < 4; ++qq) {
    if (sq == qq) {
#pragma unroll
      for (int n = 0; n < 5; ++n) {
#pragma unroll
        for (int rr = 0; rr < 4; ++rr) {
          const int row = 16 * pp + 4 * g + rr;
          const int col = 16 * n + l15;
          float v = ctx[n][rr] * gg[rr];
          if (qq == 0) cacc[row * 84 + col] = v;
          else         cacc[row * 84 + col] += v;
        }
      }
    }
    __syncthreads();
  }
  {
    const int op = tid >> 4, oc = tid & 15;
    float Mv = fmaxf(fmaxf(mst[op], mst[64 + op]), fmaxf(mst[128 + op], mst[192 + op]));
    float Lv = lst[op] * E2(mst[op] - Mv) + lst[64 + op] * E2(mst[64 + op] - Mv)
             + lst[128 + op] * E2(mst[128 + op] - Mv) + lst[192 + op] * E2(mst[192 + op] - Mv);
    float inv = 1.0f / Lv;
    float* orow = out + ((size_t)b * NP + op) * ND + oc * 5;
    const float* crow = cacc + op * 84 + oc * 5;
#pragma unroll
    for (int i = 0; i < 5; ++i) orow[i] = crow[i] * inv;
  }
}

extern "C" void kernel_launch(void* const* d_in, const int* in_sizes, int n_in,
                              void* d_out, int out_size, void* d_ws, size_t ws_size,
                              hipStream_t stream) {
  (void)in_sizes; (void)n_in; (void)out_size; (void)d_ws; (void)ws_size;
  const float* enc  = (const float*)d_in[0];
  const float* dec  = (const float*)d_in[1];
  const int*   mask = (const int*)d_in[2];
  const float* W    = (const float*)d_in[3];
  float* out = (float*)d_out;
  DecoderAttention_62989990363717_kernel<<<dim3(NB), dim3(NTHREADS), 0, stream>>>(
      enc, dec, mask, W, out);
}